// Round 5
// baseline (671.531 us; speedup 1.0000x reference)
//
#include <hip/hip_runtime.h>
#include <hip/hip_bf16.h>
#include <stdint.h>

typedef __hip_bfloat16 bf16;
typedef __attribute__((ext_vector_type(8))) short bf16x8;   // 8 bf16 = 4 VGPRs
typedef __attribute__((ext_vector_type(4))) float f32x4;

static constexpr int Mtot = 8192;   // B*T
static constexpr int Ktot = 4096;   // DIN
static constexpr int Ntot = 4096;   // DOUT
static constexpr int BM = 256, BN = 256, BK = 64;
static constexpr int NKT = Ktot / BK;           // 64 K-tiles
static constexpr int WEFF_BLOCKS = Ntot * 2;    // 8192 (half-row per block)

__device__ __forceinline__ void gl_lds16(const void* g, void* l) {
  __builtin_amdgcn_global_load_lds(
      (const __attribute__((address_space(1))) void*)g,
      (__attribute__((address_space(3))) void*)l,
      16, 0, 0);
}

__device__ __forceinline__ uint32_t bf16pair(float a, float b) {
  __hip_bfloat16 ha = __float2bfloat16(a), hb = __float2bfloat16(b);
  uint16_t ia, ib;
  __builtin_memcpy(&ia, &ha, 2);
  __builtin_memcpy(&ib, &hb, 2);
  return (uint32_t)ia | ((uint32_t)ib << 16);
}

// ---------- stage 0: M[o][2] = (U S R)[o][:]  (tiny; M stashed in out[0:32KB]) ----------
__global__ __launch_bounds__(256) void mprep_kernel(const float* __restrict__ U,
                                                    const float* __restrict__ S,
                                                    const float* __restrict__ P,
                                                    const float* __restrict__ v,
                                                    float* __restrict__ M) {
  float R0 = 0.f, R1 = 0.f, R2 = 0.f, R3 = 0.f;
#pragma unroll
  for (int u = 0; u < 16; ++u) {
    float vu = v[u];
    R0 += vu * P[u * 4 + 0];
    R1 += vu * P[u * 4 + 1];
    R2 += vu * P[u * 4 + 2];
    R3 += vu * P[u * 4 + 3];
  }
  float SR00 = S[0] * R0 + S[1] * R2, SR01 = S[0] * R1 + S[1] * R3;
  float SR10 = S[2] * R0 + S[3] * R2, SR11 = S[2] * R1 + S[3] * R3;
  const int o = blockIdx.x * 256 + threadIdx.x;           // 0..4095
  const float u0 = U[o * 2 + 0], u1 = U[o * 2 + 1];
  ((float2*)M)[o] = make_float2(u0 * SR00 + u1 * SR10, u0 * SR01 + u1 * SR11);
}

// ---------- stage 1: W_eff = bf16(W + M @ Vh) only (x-cast is fused into GEMM) ----------
__global__ __launch_bounds__(256) void prep_kernel(const float* __restrict__ W,
                                                   const float* __restrict__ Vh,
                                                   const float* __restrict__ M,
                                                   bf16* __restrict__ Wp) {
  const int bid = blockIdx.x;              // 0..8191
  const int t = threadIdx.x;
  const int o = bid >> 1;                  // row 0..4095 (uniform per block)
  const int cb = (bid & 1) * 2048 + 4 * t; // col base, lane-contiguous float4
  const float2 Mo = ((const float2*)M)[o];

  const float* wrow = W + (size_t)o * Ktot;
  const float4 w0 = *(const float4*)(wrow + cb);
  const float4 w1 = *(const float4*)(wrow + cb + 1024);
  const float4 a0 = *(const float4*)(Vh + cb);
  const float4 a1 = *(const float4*)(Vh + cb + 1024);
  const float4 b0 = *(const float4*)(Vh + Ktot + cb);
  const float4 b1 = *(const float4*)(Vh + Ktot + cb + 1024);

  uint2 p0, p1;
  p0.x = bf16pair(w0.x + Mo.x * a0.x + Mo.y * b0.x,
                  w0.y + Mo.x * a0.y + Mo.y * b0.y);
  p0.y = bf16pair(w0.z + Mo.x * a0.z + Mo.y * b0.z,
                  w0.w + Mo.x * a0.w + Mo.y * b0.w);
  p1.x = bf16pair(w1.x + Mo.x * a1.x + Mo.y * b1.x,
                  w1.y + Mo.x * a1.y + Mo.y * b1.y);
  p1.y = bf16pair(w1.z + Mo.x * a1.z + Mo.y * b1.z,
                  w1.w + Mo.x * a1.w + Mo.y * b1.w);
  *(uint2*)(Wp + (size_t)o * Ktot + cb) = p0;
  *(uint2*)(Wp + (size_t)o * Ktot + cb + 1024) = p1;
}

// ---------- main GEMM: 256x256, BK=64, 8 waves, 8-phase, FUSED A-cast ----------
// A-operand staged from f32 x via reg-staging (4x dwordx4 -> 8 cvt -> 2 ds_write_b128)
// at the same phase slots / same swizzled LDS layout as before; read side unchanged.
// B-operand unchanged (global_load_lds from Wp). Mixed vmcnt ledger re-derived:
//   steady: p1 vmcnt(4), p4 vmcnt(12) [pre-barrier, cross-wave B-residency],
//           p5 vmcnt(8), p6 vmcnt(6), p8 vmcnt(8).
// Writer phases drain lgkmcnt to counted values (12/4/0) pre-barrier so ds_writes
// are visible while ds_reads stay pending.

#define SCHEDB __builtin_amdgcn_sched_barrier(0)
#define BAR do { SCHEDB; __builtin_amdgcn_s_barrier(); SCHEDB; } while (0)
#define LG0 do { asm volatile("s_waitcnt lgkmcnt(0)" ::: "memory"); SCHEDB; } while (0)
#define LGN(n) do { asm volatile("s_waitcnt lgkmcnt(" #n ")" ::: "memory"); } while (0)
#define WVM(n) do { asm volatile("s_waitcnt vmcnt(" #n ")" ::: "memory"); } while (0)

__global__ __launch_bounds__(512, 2) void gemm_kernel(const float* __restrict__ x,
                                                      const bf16* __restrict__ Bt,
                                                      const float* __restrict__ bias,
                                                      float* __restrict__ out) {
  __shared__ __align__(16) bf16 As[2][BM * BK];   // 2 x 32 KiB
  __shared__ __align__(16) bf16 Bs[2][BN * BK];   // 2 x 32 KiB

  const int tid = (int)threadIdx.x;
  const int lane = tid & 63;
  const int w = tid >> 6;                 // wave 0..7
  const int wr = w >> 2;                  // 0..1 -> 128 M-rows
  const int wc = w & 3;                   // 0..3 -> 64 N-cols

  // ---- XCD-cooperative tile mapping (bijective over 512 wgs) ----
  const int bid = (int)blockIdx.x;        // 0..511
  const int xcd = bid & 7;                // HW: XCC_ID = bid % 8
  const int ord = bid >> 3;               // arrival order within XCD, 0..63
  const int rnd = ord >> 5;               // round 0..1 (1 wg/CU, 32 CUs/XCD)
  const int slt = ord & 31;               // slot within round
  const int mt = rnd * 16 + (xcd >> 1) * 4 + (slt >> 3);  // 0..31
  const int nt = (xcd & 1) * 8 + (slt & 7);               // 0..15
  const int m0 = mt * BM;
  const int n0 = nt * BN;

  // ---- B staging (unchanged): wave w covers 16 rows of each 128-row half ----
  const int l8 = lane >> 3;                       // 0..7
  const int swcol = ((lane & 7) ^ l8) << 3;       // element offset (row&7 == l8)
  const bf16* gB = Bt + (size_t)(n0 + w * 16 + l8) * Ktot + swcol;

  // ---- A staging (fused cast): thread t -> unit row ar = t>>2, 16 floats ----
  const int ar = tid >> 2;                        // 0..127 row within unit
  const int ac = (tid & 3) << 4;                  // float col base (0/16/32/48)
  const float* gAx = x + (size_t)(m0 + ar) * Ktot + ac;
  const int c0 = (tid & 3) << 5;                  // logical byte base in row
  const int asw = (ar & 7) << 4;                  // XOR swizzle (16B chunks)
  const int aw0 = ar * 128 + (c0 ^ asw);
  const int aw1 = ar * 128 + ((c0 + 16) ^ asw);

  // ---- compute-side lane addressing (ds_read_b128, swizzled; unchanged) ----
  const int fm = lane & 15;
  const int q = lane >> 4;                 // k-chunk 0..3
  const int rx = (fm & 7) << 4;
  const int clo = (q * 16) ^ (rx & 48);
  const int aoff0 = (wr * 128 + fm) * 128 + clo + (rx & 64);        // ks=0
  const int aoff1 = (wr * 128 + fm) * 128 + clo + (64 ^ (rx & 64)); // ks=1
  const int boff0 = (wc * 64 + fm) * 128 + clo + (rx & 64);
  const int boff1 = (wc * 64 + fm) * 128 + clo + (64 ^ (rx & 64));

#define IA0(ub, kt) do { \
    const float* _g = gAx + (size_t)((ub) * 128) * Ktot + (kt) * 64; \
    sA0[0] = *(const float4*)(_g + 0);  sA0[1] = *(const float4*)(_g + 4); \
    sA0[2] = *(const float4*)(_g + 8);  sA0[3] = *(const float4*)(_g + 12); \
  } while (0)
#define IA1(ub, kt) do { \
    const float* _g = gAx + (size_t)((ub) * 128) * Ktot + (kt) * 64; \
    sA1[0] = *(const float4*)(_g + 0);  sA1[1] = *(const float4*)(_g + 4); \
    sA1[2] = *(const float4*)(_g + 8);  sA1[3] = *(const float4*)(_g + 12); \
  } while (0)
#define WRA0(BUF, ub) do { \
    char* _b = (char*)(&As[BUF][0]) + (ub) * 16384; \
    uint4 _lo, _hi; \
    _lo.x = bf16pair(sA0[0].x, sA0[0].y); _lo.y = bf16pair(sA0[0].z, sA0[0].w); \
    _lo.z = bf16pair(sA0[1].x, sA0[1].y); _lo.w = bf16pair(sA0[1].z, sA0[1].w); \
    _hi.x = bf16pair(sA0[2].x, sA0[2].y); _hi.y = bf16pair(sA0[2].z, sA0[2].w); \
    _hi.z = bf16pair(sA0[3].x, sA0[3].y); _hi.w = bf16pair(sA0[3].z, sA0[3].w); \
    *(uint4*)(_b + aw0) = _lo; *(uint4*)(_b + aw1) = _hi; \
  } while (0)
#define WRA1(BUF, ub) do { \
    char* _b = (char*)(&As[BUF][0]) + (ub) * 16384; \
    uint4 _lo, _hi; \
    _lo.x = bf16pair(sA1[0].x, sA1[0].y); _lo.y = bf16pair(sA1[0].z, sA1[0].w); \
    _lo.z = bf16pair(sA1[1].x, sA1[1].y); _lo.w = bf16pair(sA1[1].z, sA1[1].w); \
    _hi.x = bf16pair(sA1[2].x, sA1[2].y); _hi.y = bf16pair(sA1[2].z, sA1[2].w); \
    _hi.z = bf16pair(sA1[3].x, sA1[3].y); _hi.w = bf16pair(sA1[3].z, sA1[3].w); \
    *(uint4*)(_b + aw0) = _lo; *(uint4*)(_b + aw1) = _hi; \
  } while (0)
#define STB(BUF, half, kt) do { \
    const bf16* _g = gB + (size_t)((half) * 128) * Ktot + (kt) * 64; \
    char* _l = (char*)(&Bs[BUF][0]) + (half) * 16384 + w * 2048; \
    gl_lds16(_g, _l); \
    gl_lds16(_g + (size_t)8 * Ktot, _l + 1024); \
  } while (0)

#define RD_A(dst, BUF, mh) do { \
    const char* _p = (const char*)(&As[BUF][0]) + (mh) * 8192; \
    _Pragma("unroll") for (int _i = 0; _i < 4; ++_i) { \
      dst[_i][0] = *(const bf16x8*)(_p + _i * 2048 + aoff0); \
      dst[_i][1] = *(const bf16x8*)(_p + _i * 2048 + aoff1); \
    } } while (0)
#define RD_B(dst, BUF, nh) do { \
    const char* _p = (const char*)(&Bs[BUF][0]) + (nh) * 4096; \
    _Pragma("unroll") for (int _j = 0; _j < 2; ++_j) { \
      dst[_j][0] = *(const bf16x8*)(_p + _j * 2048 + boff0); \
      dst[_j][1] = *(const bf16x8*)(_p + _j * 2048 + boff1); \
    } } while (0)

#define MFMA_Q(AV, BV, MH, NH) do { \
    __builtin_amdgcn_s_setprio(1); \
    _Pragma("unroll") for (int _i = 0; _i < 4; ++_i) \
    _Pragma("unroll") for (int _j = 0; _j < 2; ++_j) { \
      acc[(MH) * 4 + _i][(NH) * 2 + _j] = __builtin_amdgcn_mfma_f32_16x16x32_bf16( \
          AV[_i][0], BV[_j][0], acc[(MH) * 4 + _i][(NH) * 2 + _j], 0, 0, 0); \
      acc[(MH) * 4 + _i][(NH) * 2 + _j] = __builtin_amdgcn_mfma_f32_16x16x32_bf16( \
          AV[_i][1], BV[_j][1], acc[(MH) * 4 + _i][(NH) * 2 + _j], 0, 0, 0); \
    } \
    __builtin_amdgcn_s_setprio(0); \
  } while (0)

  f32x4 acc[8][4];
#pragma unroll
  for (int i = 0; i < 8; ++i)
#pragma unroll
    for (int j = 0; j < 4; ++j) acc[i][j] = {0.f, 0.f, 0.f, 0.f};

  bf16x8 a[4][2], b0[2][2], b1[2][2];
  float4 sA0[4], sA1[4];

  // ---- prologue ----
  // K0: A0,A1 (reg) + B0,B1 (gload_lds); write A0/A1; then K1: A0 (write), A1+B0+B1 in flight
  IA0(0, 0); IA1(1, 0);
  STB(0, 0, 0); STB(0, 1, 0);
  WVM(8);  WRA0(0, 0);          // K0.A0 -> buf0
  WVM(4);  WRA1(0, 1);          // K0.A1 -> buf0
  IA0(0, 1);                    // K1.A0
  WVM(0);  WRA0(1, 0);          // K1.A0 -> buf1 (also retires K0.B0/B1 gloads)
  IA1(1, 1);                    // K1.A1 (stays in flight)
  STB(1, 0, 1); STB(1, 1, 1);   // K1.B0/B1 (stay in flight)
  LGN(0);                       // all ds_writes visible
  BAR;
  // invariant: buf0 = K0 resident; queue = {K1.A1(4), K1.B0(2), K1.B1(2)}

  for (int it = 0; it < 31; ++it) {
    const int k2 = 2 * it + 2;
    const int k3 = 2 * it + 3;
    // p1: write odd.A1 -> buf1; compute quad (0,0) of even tile (buf0)
    WVM(4); WRA1(1, 1);
    RD_A(a, 0, 0); RD_B(b0, 0, 0);
    LGN(12); BAR; LG0; MFMA_Q(a, b0, 0, 0); BAR;
    // p2
    RD_B(b1, 0, 1);
    BAR; LG0; MFMA_Q(a, b1, 0, 1); BAR;
    // p3: issue next-even A0; gload next-even B0
    IA0(0, k2); STB(0, 0, k2);
    RD_A(a, 0, 1);
    BAR; LG0; MFMA_Q(a, b0, 1, 0); BAR;
    // p4: issue next-even A1; gload next-even B1; pre-barrier retire odd.B0/B1
    IA1(1, k2); STB(0, 1, k2);
    BAR; MFMA_Q(a, b1, 1, 1); SCHEDB; WVM(12); BAR;
    // p5: write next-even A0 -> buf0; compute quad (0,0) of odd tile (buf1)
    WVM(8); WRA0(0, 0);
    RD_A(a, 1, 0); RD_B(b0, 1, 0);
    LGN(12); BAR; LG0; MFMA_Q(a, b0, 0, 0); BAR;
    // p6: issue next-odd A0; write next-even A1 -> buf0
    IA0(0, k3);
    WVM(6); WRA1(0, 1);
    RD_B(b1, 1, 1);
    LGN(4); BAR; LG0; MFMA_Q(a, b1, 0, 1); BAR;
    // p7: issue next-odd A1; gload next-odd B0
    IA1(1, k3); STB(1, 0, k3);
    RD_A(a, 1, 1);
    BAR; LG0; MFMA_Q(a, b0, 1, 0); BAR;
    // p8: gload next-odd B1; write next-odd A0 -> buf1; retire even.B1 + odd.A0
    STB(1, 1, k3);
    WVM(8); WRA0(1, 0);
    LGN(0); BAR; MFMA_Q(a, b1, 1, 1); BAR;
  }

  // ---- tail: k=62 (buf0), k=63 (buf1); queue = {K63.A1(4), K63.B0(2), K63.B1(2)} ----
  WVM(4); WRA1(1, 1);
  RD_A(a, 0, 0); RD_B(b0, 0, 0);
  LGN(12); BAR; LG0; MFMA_Q(a, b0, 0, 0); BAR;
  RD_B(b1, 0, 1);
  BAR; LG0; MFMA_Q(a, b1, 0, 1); BAR;
  RD_A(a, 0, 1);
  BAR; LG0; MFMA_Q(a, b0, 1, 0); BAR;
  BAR; MFMA_Q(a, b1, 1, 1); SCHEDB; WVM(0); BAR;
  RD_A(a, 1, 0); RD_B(b0, 1, 0);
  BAR; LG0; MFMA_Q(a, b0, 0, 0); BAR;
  RD_B(b1, 1, 1);
  BAR; LG0; MFMA_Q(a, b1, 0, 1); BAR;
  RD_A(a, 1, 1);
  BAR; LG0; MFMA_Q(a, b0, 1, 0); BAR;
  MFMA_Q(a, b1, 1, 1);

  // ---- epilogue: C/D layout col = lane&15 (N), row = (lane>>4)*4 + reg (M) ----
#pragma unroll
  for (int jb = 0; jb < 4; ++jb) {
    const int gn = n0 + wc * 64 + jb * 16 + fm;
    const float bj = bias[gn];
#pragma unroll
    for (int ia = 0; ia < 8; ++ia) {
      float* o = out + (size_t)(m0 + wr * 128 + ia * 16 + q * 4) * Ntot + gn;
#pragma unroll
      for (int r = 0; r < 4; ++r) o[(size_t)r * Ntot] = acc[ia][jb][r] + bj;
    }
  }

#undef IA0
#undef IA1
#undef WRA0
#undef WRA1
#undef STB
#undef RD_A
#undef RD_B
#undef MFMA_Q
}

extern "C" void kernel_launch(void* const* d_in, const int* in_sizes, int n_in,
                              void* d_out, int out_size, void* d_ws, size_t ws_size,
                              hipStream_t stream) {
  const float* x  = (const float*)d_in[0];
  const float* W  = (const float*)d_in[1];
  const float* b  = (const float*)d_in[2];
  const float* U  = (const float*)d_in[3];
  const float* S  = (const float*)d_in[4];
  const float* Vh = (const float*)d_in[5];
  const float* P  = (const float*)d_in[6];
  const float* v  = (const float*)d_in[7];
  float* out = (float*)d_out;

  bf16* Wp = (bf16*)d_ws;                 // 33,554,432 B (xb eliminated)
  // M[4096][2] lives in out[0:32KB]: written by mprep, read by prep,
  // overwritten by gemm afterwards (stream-ordered, so this is safe).
  float* M = out;

  mprep_kernel<<<16, 256, 0, stream>>>(U, S, P, v, M);
  prep_kernel<<<WEFF_BLOCKS, 256, 0, stream>>>(W, Vh, M, Wp);
  gemm_kernel<<<512, 512, 0, stream>>>(x, Wp, b, out);
}

// Round 6
// 511.171 us; speedup vs baseline: 1.3137x; 1.3137x over previous
//
#include <hip/hip_runtime.h>
#include <hip/hip_bf16.h>
#include <stdint.h>

typedef __hip_bfloat16 bf16;
typedef __attribute__((ext_vector_type(8))) short bf16x8;   // 8 bf16 = 4 VGPRs
typedef __attribute__((ext_vector_type(4))) float f32x4;

static constexpr int Mtot = 8192;   // B*T
static constexpr int Ktot = 4096;   // DIN
static constexpr int Ntot = 4096;   // DOUT
static constexpr int BM = 256, BN = 256, BK = 64;
static constexpr int NKT = Ktot / BK;           // 64 K-tiles
static constexpr int CAST_BLOCKS = (Mtot * Ktot) / 2048;     // 16384
static constexpr int WEFF_BLOCKS = Ntot * 2;                 // 8192

__device__ __forceinline__ void gl_lds16(const void* g, void* l) {
  __builtin_amdgcn_global_load_lds(
      (const __attribute__((address_space(1))) void*)g,
      (__attribute__((address_space(3))) void*)l,
      16, 0, 0);
}

__device__ __forceinline__ uint32_t bf16pair(float a, float b) {
  __hip_bfloat16 ha = __float2bfloat16(a), hb = __float2bfloat16(b);
  uint16_t ia, ib;
  __builtin_memcpy(&ia, &ha, 2);
  __builtin_memcpy(&ib, &hb, 2);
  return (uint32_t)ia | ((uint32_t)ib << 16);
}

// ---------- stage 0: M[o][2] = (U S R)[o][:]  (tiny; M stashed in out[0:32KB]) ----------
__global__ __launch_bounds__(256) void mprep_kernel(const float* __restrict__ U,
                                                    const float* __restrict__ S,
                                                    const float* __restrict__ P,
                                                    const float* __restrict__ v,
                                                    float* __restrict__ M) {
  float R0 = 0.f, R1 = 0.f, R2 = 0.f, R3 = 0.f;
#pragma unroll
  for (int u = 0; u < 16; ++u) {
    float vu = v[u];
    R0 += vu * P[u * 4 + 0];
    R1 += vu * P[u * 4 + 1];
    R2 += vu * P[u * 4 + 2];
    R3 += vu * P[u * 4 + 3];
  }
  float SR00 = S[0] * R0 + S[1] * R2, SR01 = S[0] * R1 + S[1] * R3;
  float SR10 = S[2] * R0 + S[3] * R2, SR11 = S[2] * R1 + S[3] * R3;
  const int o = blockIdx.x * 256 + threadIdx.x;           // 0..4095
  const float u0 = U[o * 2 + 0], u1 = U[o * 2 + 1];
  ((float2*)M)[o] = make_float2(u0 * SR00 + u1 * SR10, u0 * SR01 + u1 * SR11);
}

// ---------- stage 1: cast x -> bf16  AND  W_eff -> bf16 (all lane-contiguous) ----------
__global__ __launch_bounds__(256) void prep_kernel(const float* __restrict__ x,
                                                   bf16* __restrict__ xb,
                                                   const float* __restrict__ W,
                                                   const float* __restrict__ Vh,
                                                   const float* __restrict__ M,
                                                   bf16* __restrict__ Wp) {
  const int bid = blockIdx.x;
  const int t = threadIdx.x;
  if (bid < CAST_BLOCKS) {
    const size_t chunk = (size_t)bid * 2048;
    const float4 a = *(const float4*)(x + chunk + 4 * t);
    const float4 b = *(const float4*)(x + chunk + 1024 + 4 * t);
    uint2 p0, p1;
    p0.x = bf16pair(a.x, a.y); p0.y = bf16pair(a.z, a.w);
    p1.x = bf16pair(b.x, b.y); p1.y = bf16pair(b.z, b.w);
    *(uint2*)(xb + chunk + 4 * t) = p0;
    *(uint2*)(xb + chunk + 1024 + 4 * t) = p1;
  } else {
    const int b2 = bid - CAST_BLOCKS;        // 0..8191
    const int o = b2 >> 1;                   // row 0..4095
    const int cb = (b2 & 1) * 2048 + 4 * t;  // col base, lane-contiguous float4
    const float2 Mo = ((const float2*)M)[o];

    const float* wrow = W + (size_t)o * Ktot;
    const float4 w0 = *(const float4*)(wrow + cb);
    const float4 w1 = *(const float4*)(wrow + cb + 1024);
    const float4 a0 = *(const float4*)(Vh + cb);
    const float4 a1 = *(const float4*)(Vh + cb + 1024);
    const float4 b0 = *(const float4*)(Vh + Ktot + cb);
    const float4 b1 = *(const float4*)(Vh + Ktot + cb + 1024);

    uint2 p0, p1;
    p0.x = bf16pair(w0.x + Mo.x * a0.x + Mo.y * b0.x,
                    w0.y + Mo.x * a0.y + Mo.y * b0.y);
    p0.y = bf16pair(w0.z + Mo.x * a0.z + Mo.y * b0.z,
                    w0.w + Mo.x * a0.w + Mo.y * b0.w);
    p1.x = bf16pair(w1.x + Mo.x * a1.x + Mo.y * b1.x,
                    w1.y + Mo.x * a1.y + Mo.y * b1.y);
    p1.y = bf16pair(w1.z + Mo.x * a1.z + Mo.y * b1.z,
                    w1.w + Mo.x * a1.w + Mo.y * b1.w);
    *(uint2*)(Wp + (size_t)o * Ktot + cb) = p0;
    *(uint2*)(Wp + (size_t)o * Ktot + cb + 1024) = p1;
  }
}

// ---------- main GEMM: R2 base + EARLY ds_reads (one isolated change) ----------
// STAGE placement, vmcnt ledger, XCD-coop mapping, swizzle: identical to R2.
// Only the ds_read issue slots moved one phase early with counted lgkmcnt:
//   p1/p5: issue {a,b0,b1} (16 reads), post-bar lgkmcnt(4)  -> b1 stays pending
//   p2/p6: issue {a2}      (8 reads),  post-bar lgkmcnt(8)  -> retires b1 only
//   p3/p7: lgkmcnt(0) (a2 landed a full phase ago -> free); p4/p8: no reads.

#define SCHEDB __builtin_amdgcn_sched_barrier(0)
#define BAR do { SCHEDB; __builtin_amdgcn_s_barrier(); SCHEDB; } while (0)
#define LGW(n) do { asm volatile("s_waitcnt lgkmcnt(" #n ")" ::: "memory"); SCHEDB; } while (0)
#define LGP(n) do { asm volatile("s_waitcnt lgkmcnt(" #n ")" ::: "memory"); } while (0)
#define WVM(n) do { asm volatile("s_waitcnt vmcnt(" #n ")" ::: "memory"); } while (0)

__global__ __launch_bounds__(512, 2) void gemm_kernel(const bf16* __restrict__ A,
                                                      const bf16* __restrict__ Bt,
                                                      const float* __restrict__ bias,
                                                      float* __restrict__ out) {
  __shared__ __align__(16) bf16 As[2][BM * BK];   // 2 x 32 KiB
  __shared__ __align__(16) bf16 Bs[2][BN * BK];   // 2 x 32 KiB

  const int tid = (int)threadIdx.x;
  const int lane = tid & 63;
  const int w = tid >> 6;                 // wave 0..7
  const int wr = w >> 2;                  // 0..1 -> 128 M-rows
  const int wc = w & 3;                   // 0..3 -> 64 N-cols

  // ---- XCD-cooperative tile mapping (bijective over 512 wgs) ----
  const int bid = (int)blockIdx.x;        // 0..511
  const int xcd = bid & 7;
  const int ord = bid >> 3;
  const int rnd = ord >> 5;
  const int slt = ord & 31;
  const int mt = rnd * 16 + (xcd >> 1) * 4 + (slt >> 3);  // 0..31
  const int nt = (xcd & 1) * 8 + (slt & 7);               // 0..15
  const int m0 = mt * BM;
  const int n0 = nt * BN;

  // ---- staging addressing ----
  const int l8 = lane >> 3;
  const int swcol = ((lane & 7) ^ l8) << 3;
  const bf16* gA = A + (size_t)(m0 + w * 16 + l8) * Ktot + swcol;
  const bf16* gB = Bt + (size_t)(n0 + w * 16 + l8) * Ktot + swcol;

  // ---- compute-side lane addressing ----
  const int fm = lane & 15;
  const int q = lane >> 4;
  const int rx = (fm & 7) << 4;
  const int clo = (q * 16) ^ (rx & 48);
  const int aoff0 = (wr * 128 + fm) * 128 + clo + (rx & 64);
  const int aoff1 = (wr * 128 + fm) * 128 + clo + (64 ^ (rx & 64));
  const int boff0 = (wc * 64 + fm) * 128 + clo + (rx & 64);
  const int boff1 = (wc * 64 + fm) * 128 + clo + (64 ^ (rx & 64));

#define STA(BUF, half, kt) do { \
    const bf16* _g = gA + (size_t)((half) * 128) * Ktot + (kt) * 64; \
    char* _l = (char*)(&As[BUF][0]) + (half) * 16384 + w * 2048; \
    gl_lds16(_g, _l); \
    gl_lds16(_g + (size_t)8 * Ktot, _l + 1024); \
  } while (0)
#define STB(BUF, half, kt) do { \
    const bf16* _g = gB + (size_t)((half) * 128) * Ktot + (kt) * 64; \
    char* _l = (char*)(&Bs[BUF][0]) + (half) * 16384 + w * 2048; \
    gl_lds16(_g, _l); \
    gl_lds16(_g + (size_t)8 * Ktot, _l + 1024); \
  } while (0)
#define STAGE_H(BUF, h, kt) do { \
    if ((h) == 0) STA(BUF, 0, kt); else if ((h) == 1) STA(BUF, 1, kt); \
    else if ((h) == 2) STB(BUF, 0, kt); else STB(BUF, 1, kt); } while (0)

#define RD_A(dst, BUF, mh) do { \
    const char* _p = (const char*)(&As[BUF][0]) + (mh) * 8192; \
    _Pragma("unroll") for (int _i = 0; _i < 4; ++_i) { \
      dst[_i][0] = *(const bf16x8*)(_p + _i * 2048 + aoff0); \
      dst[_i][1] = *(const bf16x8*)(_p + _i * 2048 + aoff1); \
    } } while (0)
#define RD_B(dst, BUF, nh) do { \
    const char* _p = (const char*)(&Bs[BUF][0]) + (nh) * 4096; \
    _Pragma("unroll") for (int _j = 0; _j < 2; ++_j) { \
      dst[_j][0] = *(const bf16x8*)(_p + _j * 2048 + boff0); \
      dst[_j][1] = *(const bf16x8*)(_p + _j * 2048 + boff1); \
    } } while (0)

#define MFMA_Q(AV, BV, MH, NH) do { \
    __builtin_amdgcn_s_setprio(1); \
    _Pragma("unroll") for (int _i = 0; _i < 4; ++_i) \
    _Pragma("unroll") for (int _j = 0; _j < 2; ++_j) { \
      acc[(MH) * 4 + _i][(NH) * 2 + _j] = __builtin_amdgcn_mfma_f32_16x16x32_bf16( \
          AV[_i][0], BV[_j][0], acc[(MH) * 4 + _i][(NH) * 2 + _j], 0, 0, 0); \
      acc[(MH) * 4 + _i][(NH) * 2 + _j] = __builtin_amdgcn_mfma_f32_16x16x32_bf16( \
          AV[_i][1], BV[_j][1], acc[(MH) * 4 + _i][(NH) * 2 + _j], 0, 0, 0); \
    } \
    __builtin_amdgcn_s_setprio(0); \
  } while (0)

  f32x4 acc[8][4];
#pragma unroll
  for (int i = 0; i < 8; ++i)
#pragma unroll
    for (int j = 0; j < 4; ++j) acc[i][j] = {0.f, 0.f, 0.f, 0.f};

  bf16x8 a[4][2], a2[4][2], b0[2][2], b1[2][2];

  // ---- prologue: K-tile 0 fully, then 3 half-tiles of K-tile 1 ----
  STAGE_H(0, 0, 0); STAGE_H(0, 1, 0); STAGE_H(0, 2, 0); STAGE_H(0, 3, 0);
  STAGE_H(1, 2, 1); STAGE_H(1, 3, 1); STAGE_H(1, 0, 1);
  WVM(6);   // K-tile 0 resident; 6 loads in flight
  BAR;

  // invariant at loop head: buf0 = even K-tile resident; {odd B0,B1,A0} in flight
  for (int it = 0; it < 31; ++it) {
    const int k1 = 2 * it + 1;
    const int k2 = 2 * it + 2;
    const int k3 = 2 * it + 3;
    // p1: issue a,b0,b1 (16 reads); consume a,b0
    RD_A(a, 0, 0); RD_B(b0, 0, 0); RD_B(b1, 0, 1); STAGE_H(1, 1, k1); LGP(8);
    BAR; LGW(4); MFMA_Q(a, b0, 0, 0); BAR;
    // p2: issue a2 (8 reads); consume b1 (retire exactly b1: 12 outstanding -> 8)
    RD_A(a2, 0, 1);
    BAR; LGW(8); MFMA_Q(a, b1, 0, 1); BAR;
    // p3: a2 landed a full phase ago
    STAGE_H(0, 2, k2);
    BAR; LGW(0); MFMA_Q(a2, b0, 1, 0); BAR;
    // p4: no reads; retire K-odd A1 (oldest of 6 vmem) pre-barrier
    STAGE_H(0, 3, k2);
    BAR; MFMA_Q(a2, b1, 1, 1); SCHEDB; WVM(4); BAR;
    // p5: buf1 (odd tile) reads; all operands resident (A1 via p4, B0/B1 via prev p8)
    RD_A(a, 1, 0); RD_B(b0, 1, 0); RD_B(b1, 1, 1); STAGE_H(0, 0, k2); LGP(8);
    BAR; LGW(4); MFMA_Q(a, b0, 0, 0); BAR;
    // p6: issue a2 of buf1
    RD_A(a2, 1, 1); STAGE_H(0, 1, k2);
    BAR; LGW(8); MFMA_Q(a, b1, 0, 1); BAR;
    // p7
    STAGE_H(1, 2, k3);
    BAR; LGW(0); MFMA_Q(a2, b0, 1, 0); BAR;
    // p8: retire next-even K-tile fully (oldest 8 of 14 vmem)
    STAGE_H(1, 3, k3); STAGE_H(1, 0, k3);
    BAR; MFMA_Q(a2, b1, 1, 1); SCHEDB; WVM(6); BAR;
  }

  // ---- tail: k=62 (buf0), k=63 (buf1); queue = {K63.A1, B0 already...} ----
  RD_A(a, 0, 0); RD_B(b0, 0, 0); RD_B(b1, 0, 1); STAGE_H(1, 1, 63); LGP(8);
  BAR; LGW(4); MFMA_Q(a, b0, 0, 0); BAR;
  RD_A(a2, 0, 1);
  BAR; LGW(8); MFMA_Q(a, b1, 0, 1); BAR;
  BAR; LGW(0); MFMA_Q(a2, b0, 1, 0); BAR;
  BAR; MFMA_Q(a2, b1, 1, 1); SCHEDB; WVM(0); BAR;
  RD_A(a, 1, 0); RD_B(b0, 1, 0); RD_B(b1, 1, 1); LGP(8);
  BAR; LGW(4); MFMA_Q(a, b0, 0, 0); BAR;
  RD_A(a2, 1, 1);
  BAR; LGW(8); MFMA_Q(a, b1, 0, 1); BAR;
  BAR; LGW(0); MFMA_Q(a2, b0, 1, 0); BAR;
  MFMA_Q(a2, b1, 1, 1);

  // ---- epilogue: C/D layout col = lane&15 (N), row = (lane>>4)*4 + reg (M) ----
#pragma unroll
  for (int jb = 0; jb < 4; ++jb) {
    const int gn = n0 + wc * 64 + jb * 16 + fm;
    const float bj = bias[gn];
#pragma unroll
    for (int ia = 0; ia < 8; ++ia) {
      float* o = out + (size_t)(m0 + wr * 128 + ia * 16 + q * 4) * Ntot + gn;
#pragma unroll
      for (int r = 0; r < 4; ++r) o[(size_t)r * Ntot] = acc[ia][jb][r] + bj;
    }
  }

#undef STA
#undef STB
#undef STAGE_H
#undef RD_A
#undef RD_B
#undef MFMA_Q
}

extern "C" void kernel_launch(void* const* d_in, const int* in_sizes, int n_in,
                              void* d_out, int out_size, void* d_ws, size_t ws_size,
                              hipStream_t stream) {
  const float* x  = (const float*)d_in[0];
  const float* W  = (const float*)d_in[1];
  const float* b  = (const float*)d_in[2];
  const float* U  = (const float*)d_in[3];
  const float* S  = (const float*)d_in[4];
  const float* Vh = (const float*)d_in[5];
  const float* P  = (const float*)d_in[6];
  const float* v  = (const float*)d_in[7];
  float* out = (float*)d_out;

  bf16* xb = (bf16*)d_ws;                                    // 67,108,864 B
  bf16* Wp = (bf16*)((char*)d_ws + (size_t)Mtot * Ktot * 2); // +33,554,432 B
  // M[4096][2] lives in out[0:32KB]: written by mprep, read by prep,
  // overwritten by gemm afterwards (stream-ordered, so this is safe).
  float* M = out;

  mprep_kernel<<<16, 256, 0, stream>>>(U, S, P, v, M);
  prep_kernel<<<CAST_BLOCKS + WEFF_BLOCKS, 256, 0, stream>>>(x, xb, W, Vh, M, Wp);
  gemm_kernel<<<512, 512, 0, stream>>>(xb, Wp, b, out);
}